// Round 1
// baseline (355.425 us; speedup 1.0000x reference)
//
#include <hip/hip_runtime.h>

typedef __bf16 bf16;
typedef __attribute__((ext_vector_type(8))) __bf16 bf16x8;
typedef __attribute__((ext_vector_type(4))) __bf16 bf16x4;
typedef __attribute__((ext_vector_type(4))) float f32x4;

#define MFMA16(a, b, c) __builtin_amdgcn_mfma_f32_16x16x32_bf16(a, b, c, 0, 0, 0)

// ---------------------------------------------------------------------------
// prep: Xbf[4][4096][256] = bf16(concat(prev_x, x));  Wqkvt[768][256],
// Woutt[256][256] = bf16(W^T)
// ---------------------------------------------------------------------------
__global__ __launch_bounds__(256) void prep_kernel(
    const float* __restrict__ x, const float* __restrict__ px,
    const float* __restrict__ Wqkv, const float* __restrict__ Wout,
    bf16* __restrict__ Xbf, bf16* __restrict__ Wqkvt, bf16* __restrict__ Woutt)
{
  int tid = blockIdx.x * 256 + threadIdx.x;
  int nth = gridDim.x * 256;
  for (int i = tid; i < (4 * 4096 * 256) / 4; i += nth) {
    int e = i << 2;
    int b = e >> 20;           // batch (S*C = 2^20)
    int r = e & 1048575;       // s*256 + c within batch
    const float* src = (r < 524288) ? (px + (b << 19) + r)
                                    : (x + (b << 19) + (r - 524288));
    float4 f = *(const float4*)src;
    bf16x4 o = { (bf16)f.x, (bf16)f.y, (bf16)f.z, (bf16)f.w };
    *(bf16x4*)(Xbf + e) = o;
  }
  for (int i = tid; i < 768 * 256; i += nth) {
    int n = i >> 8, k = i & 255;
    Wqkvt[i] = (bf16)Wqkv[k * 768 + n];
  }
  for (int i = tid; i < 256 * 256; i += nth) {
    int n = i >> 8, k = i & 255;
    Woutt[i] = (bf16)Wout[k * 256 + n];
  }
}

// ---------------------------------------------------------------------------
// GEMM: C[M][N] = A[M][256] @ Wt[N][256]^T + bias
// MODE 0: A=Xbf (M=16384, N=768) -> Q (prescaled 1/16, rows s>=2048 only,
//         row-major), K (row-major), V (transposed [d][kv])
// MODE 1: A=attn_out bf16 (M=8192, N=256) -> f32 d_out
// tile 64x128, BK=32, 4 waves (wave = 16 rows x 128 cols)
// ---------------------------------------------------------------------------
template<int MODE>
__global__ __launch_bounds__(256) void gemm_kernel(
    const bf16* __restrict__ A, const bf16* __restrict__ Wt,
    const float* __restrict__ bias,
    bf16* __restrict__ Qo, bf16* __restrict__ Ko, bf16* __restrict__ Vto,
    float* __restrict__ Fo)
{
  const int bm = blockIdx.x * 64;
  const int n0 = blockIdx.y * 128;
  const int tid = threadIdx.x;
  const int lane = tid & 63, w = tid >> 6;
  const int l15 = lane & 15, lg = lane >> 4;

  alignas(16) __shared__ bf16 Alds[64 * 32];
  alignas(16) __shared__ bf16 Wlds[128 * 32];

  f32x4 acc[8] = {};

  for (int k0 = 0; k0 < 256; k0 += 32) {
    __syncthreads();
    {   // stage A tile 64x32 (256 x 16B chunks)
      int c = tid;
      int row = c >> 2, kc = (c & 3) << 3;
      bf16x8 v = *(const bf16x8*)(A + (size_t)(bm + row) * 256 + k0 + kc);
      *(bf16x8*)((char*)Alds + ((c << 4) ^ (((row >> 1) & 3) << 4))) = v;
    }
    #pragma unroll
    for (int it = 0; it < 2; it++) {  // stage Wt tile 128x32
      int c = it * 256 + tid;
      int row = c >> 2, kc = (c & 3) << 3;
      bf16x8 v = *(const bf16x8*)(Wt + (size_t)(n0 + row) * 256 + k0 + kc);
      *(bf16x8*)((char*)Wlds + ((c << 4) ^ (((row >> 1) & 3) << 4))) = v;
    }
    __syncthreads();
    const int arow = w * 16 + l15;
    bf16x8 afr = *(const bf16x8*)((char*)Alds +
        (((arow << 6) + (lg << 4)) ^ (((arow >> 1) & 3) << 4)));
    #pragma unroll
    for (int nt = 0; nt < 8; nt++) {
      const int wrow = nt * 16 + l15;
      bf16x8 bfr = *(const bf16x8*)((char*)Wlds +
          (((wrow << 6) + (lg << 4)) ^ (((wrow >> 1) & 3) << 4)));
      acc[nt] = MFMA16(afr, bfr, acc[nt]);
    }
  }

  // epilogue: lane holds C[m0 + r][n], r=0..3
  #pragma unroll
  for (int nt = 0; nt < 8; nt++) {
    const int n = n0 + nt * 16 + l15;
    const float bv = bias[n];
    const int m0 = bm + w * 16 + lg * 4;
    if (MODE == 0) {
      const int b = m0 >> 12;
      const int s = m0 & 4095;
      if (n < 256) {
        if (s >= 2048) {
          #pragma unroll
          for (int r = 0; r < 4; r++)
            Qo[(size_t)((b * 2048 + s - 2048 + r) * 256 + n)] =
                (bf16)((acc[nt][r] + bv) * 0.0625f);
        }
      } else if (n < 512) {
        #pragma unroll
        for (int r = 0; r < 4; r++)
          Ko[(size_t)(((b << 12) + s + r) * 256 + (n - 256))] =
              (bf16)(acc[nt][r] + bv);
      } else {
        bf16x4 st = { (bf16)(acc[nt][0] + bv), (bf16)(acc[nt][1] + bv),
                      (bf16)(acc[nt][2] + bv), (bf16)(acc[nt][3] + bv) };
        *(bf16x4*)(Vto + (size_t)((b << 8) + (n - 512)) * 4096 + s) = st;
      }
    } else {
      #pragma unroll
      for (int r = 0; r < 4; r++)
        Fo[(size_t)((m0 + r) * 256 + n)] = acc[nt][r] + bv;
    }
  }
}

// ---------------------------------------------------------------------------
// flash attention, swapped QK^T (S^T = mfma(K, Q)) so softmax + P-fragments
// are lane-local. Block = 2 waves, 32 q rows (16/wave). KV tile = 64.
// Q prescaled by 1/16. K_lds[64][256] and Vt_lds[256][64] XOR-swizzled.
// ---------------------------------------------------------------------------
__global__ __launch_bounds__(128) void attn_kernel(
    const bf16* __restrict__ Qg, const bf16* __restrict__ Kg,
    const bf16* __restrict__ Vtg, bf16* __restrict__ Og)
{
  // XCD-affine work mapping: batch b -> XCD pair {2b, 2b+1} so each XCD's L2
  // holds one batch's K+Vt (4MB).
  const int linear = blockIdx.y * gridDim.x + blockIdx.x;   // 0..255
  const int b = (linear >> 1) & 3;
  const int qb = (((linear >> 3) << 1) | (linear & 1)) * 32;

  const int tid = threadIdx.x;
  const int lane = tid & 63, w = tid >> 6;      // w in {0,1}
  const int l15 = lane & 15, lg = lane >> 4;

  alignas(16) __shared__ bf16 Klds[64 * 256];   // [kv][d], swz ^((kv&7)<<4)
  alignas(16) __shared__ bf16 Vlds[256 * 64];   // [d][kv], swz ^((d&7)<<4)

  const int qrow = qb + w * 16 + l15;           // 0..2047
  const bf16* qptr = Qg + (size_t)((b * 2048 + qrow) * 256);
  bf16x8 qf[8];
  #pragma unroll
  for (int ks = 0; ks < 8; ks++)
    qf[ks] = *(const bf16x8*)(qptr + ks * 32 + lg * 8);

  f32x4 o[16] = {};                    // O^T: d = dt*16+lg*4+r, q = l15
  float m_run = -1e30f, l_run = 0.f;

  const bf16* Kbase = Kg + ((size_t)b << 20);
  const bf16* Vbase = Vtg + ((size_t)b << 20);

  for (int kv0 = 0; kv0 < 4096; kv0 += 64) {
    __syncthreads();
    #pragma unroll 4
    for (int it = 0; it < 16; it++) {  // stage K tile [64][256]
      int c = it * 128 + tid;
      int kv = c >> 5;
      bf16x8 v = *(const bf16x8*)(Kbase + (size_t)((kv0 + kv) << 8) + ((c & 31) << 3));
      *(bf16x8*)((char*)Klds + ((c << 4) ^ ((kv & 7) << 4))) = v;
    }
    #pragma unroll 4
    for (int it = 0; it < 16; it++) {  // stage Vt tile [256][64]
      int c = it * 128 + tid;
      int d = c >> 3;
      bf16x8 v = *(const bf16x8*)(Vbase + ((size_t)d << 12) + kv0 + ((c & 7) << 3));
      *(bf16x8*)((char*)Vlds + ((c << 4) ^ ((d & 7) << 4))) = v;
    }
    __syncthreads();

    // S^T[kv][q]: p[t] holds kv = t*16 + lg*4 + r, q = l15 (lane-local q)
    f32x4 p[4] = {};
    #pragma unroll
    for (int ks = 0; ks < 8; ks++) {
      #pragma unroll
      for (int t = 0; t < 4; t++) {
        const int krow = t * 16 + l15;
        bf16x8 kf = *(const bf16x8*)((char*)Klds +
            (((krow << 9) + (ks << 6) + (lg << 4)) ^ ((krow & 7) << 4)));
        p[t] = MFMA16(kf, qf[ks], p[t]);
      }
    }

    // online softmax: per-q reduce = 2 shfl_xor (lanes l, l^16, l^32, l^48)
    float mt = -1e30f;
    #pragma unroll
    for (int t = 0; t < 4; t++)
      mt = fmaxf(mt, fmaxf(fmaxf(p[t][0], p[t][1]), fmaxf(p[t][2], p[t][3])));
    mt = fmaxf(mt, __shfl_xor(mt, 16));
    mt = fmaxf(mt, __shfl_xor(mt, 32));
    const float m_new = fmaxf(m_run, mt);
    const float alpha = __expf(m_run - m_new);
    float psum = 0.f;
    #pragma unroll
    for (int t = 0; t < 4; t++) {
      #pragma unroll
      for (int r = 0; r < 4; r++) {
        float e = __expf(p[t][r] - m_new);
        p[t][r] = e;
        psum += e;
      }
    }
    psum += __shfl_xor(psum, 16);
    psum += __shfl_xor(psum, 32);
    l_run = l_run * alpha + psum;
    m_run = m_new;
    #pragma unroll
    for (int i = 0; i < 16; i++) {
      o[i][0] *= alpha; o[i][1] *= alpha; o[i][2] *= alpha; o[i][3] *= alpha;
    }

    // P B-frags, slot map kappa(g,e) = 16*(e>>2) + 4g + (e&3): lane-local.
    bf16x8 pf[2];
    #pragma unroll
    for (int ks2 = 0; ks2 < 2; ks2++)
      #pragma unroll
      for (int e = 0; e < 8; e++)
        pf[ks2][e] = (bf16)(p[ks2 * 2 + (e >> 2)][e & 3]);

    // O^T += V^T . P^T  (A = V^T uses the same kappa: two 8B reads per frag)
    #pragma unroll
    for (int ks2 = 0; ks2 < 2; ks2++) {
      #pragma unroll
      for (int dt = 0; dt < 16; dt++) {
        const int drow = dt * 16 + l15;
        const int base = drow << 7;
        const int sw = (drow & 7) << 4;
        bf16x4 a0 = *(const bf16x4*)((char*)Vlds +
            ((base + ((ks2 * 32 + lg * 4) << 1)) ^ sw));
        bf16x4 a1 = *(const bf16x4*)((char*)Vlds +
            ((base + ((ks2 * 32 + 16 + lg * 4) << 1)) ^ sw));
        bf16x8 af = { a0[0], a0[1], a0[2], a0[3], a1[0], a1[1], a1[2], a1[3] };
        o[dt] = MFMA16(af, pf[ks2], o[dt]);
      }
    }
  }

  const float inv_l = 1.f / l_run;
  bf16* orow = Og + (size_t)((b * 2048 + qrow) * 256);
  #pragma unroll
  for (int dt = 0; dt < 16; dt++) {
    bf16x4 st = { (bf16)(o[dt][0] * inv_l), (bf16)(o[dt][1] * inv_l),
                  (bf16)(o[dt][2] * inv_l), (bf16)(o[dt][3] * inv_l) };
    *(bf16x4*)(orow + dt * 16 + lg * 4) = st;
  }
}

// ---------------------------------------------------------------------------
extern "C" void kernel_launch(void* const* d_in, const int* in_sizes, int n_in,
                              void* d_out, int out_size, void* d_ws, size_t ws_size,
                              hipStream_t stream) {
  const float* x    = (const float*)d_in[0];
  const float* px   = (const float*)d_in[1];
  const float* Wqkv = (const float*)d_in[2];
  const float* bqkv = (const float*)d_in[3];
  const float* Wout = (const float*)d_in[4];
  const float* bout = (const float*)d_in[5];
  float* out = (float*)d_out;

  char* ws = (char*)d_ws;
  bf16* Xbf   = (bf16*)(ws);                    //  8 MB  [4][4096][256]
  bf16* Qbf   = (bf16*)(ws + 8388608);          //  4 MB  [4][2048][256] *1/16
  bf16* Kbf   = (bf16*)(ws + 12582912);         //  8 MB  [4][4096][256]
  bf16* Vtbf  = (bf16*)(ws + 20971520);         //  8 MB  [4][256][4096]
  bf16* AObf  = (bf16*)(ws + 29360128);         //  4 MB  [4][2048][256]
  bf16* Wqkvt = (bf16*)(ws + 33554432);         //  384KB [768][256]
  bf16* Woutt = (bf16*)(ws + 33947648);         //  128KB [256][256]

  prep_kernel<<<dim3(512), dim3(256), 0, stream>>>(x, px, Wqkv, Wout,
                                                   Xbf, Wqkvt, Woutt);
  gemm_kernel<0><<<dim3(256, 6), dim3(256), 0, stream>>>(
      Xbf, Wqkvt, bqkv, Qbf, Kbf, Vtbf, nullptr);
  attn_kernel<<<dim3(64, 4), dim3(128), 0, stream>>>(Qbf, Kbf, Vtbf, AObf);
  gemm_kernel<1><<<dim3(128, 2), dim3(256), 0, stream>>>(
      AObf, Woutt, bout, nullptr, nullptr, nullptr, out);
}

// Round 2
// 105.558 us; speedup vs baseline: 3.3671x; 3.3671x over previous
//
#include <hip/hip_runtime.h>

typedef __bf16 bf16;
typedef __attribute__((ext_vector_type(8))) __bf16 bf16x8;
typedef __attribute__((ext_vector_type(4))) __bf16 bf16x4;
typedef __attribute__((ext_vector_type(4))) float f32x4;

#define MFMA16(a, b, c) __builtin_amdgcn_mfma_f32_16x16x32_bf16(a, b, c, 0, 0, 0)

// ---------------------------------------------------------------------------
// prep: Xbf[4][4096][256] = bf16(concat(prev_x, x));  Wqkvt[768][256],
// Woutt[256][256] = bf16(W^T)
// ---------------------------------------------------------------------------
__global__ __launch_bounds__(256) void prep_kernel(
    const float* __restrict__ x, const float* __restrict__ px,
    const float* __restrict__ Wqkv, const float* __restrict__ Wout,
    bf16* __restrict__ Xbf, bf16* __restrict__ Wqkvt, bf16* __restrict__ Woutt)
{
  int tid = blockIdx.x * 256 + threadIdx.x;
  int nth = gridDim.x * 256;
  for (int i = tid; i < (4 * 4096 * 256) / 4; i += nth) {
    int e = i << 2;
    int b = e >> 20;
    int r = e & 1048575;
    const float* src = (r < 524288) ? (px + (b << 19) + r)
                                    : (x + (b << 19) + (r - 524288));
    float4 f = *(const float4*)src;
    bf16x4 o = { (bf16)f.x, (bf16)f.y, (bf16)f.z, (bf16)f.w };
    *(bf16x4*)(Xbf + e) = o;
  }
  for (int i = tid; i < 768 * 256; i += nth) {
    int n = i >> 8, k = i & 255;
    Wqkvt[i] = (bf16)Wqkv[k * 768 + n];
  }
  for (int i = tid; i < 256 * 256; i += nth) {
    int n = i >> 8, k = i & 255;
    Woutt[i] = (bf16)Wout[k * 256 + n];
  }
}

// ---------------------------------------------------------------------------
// GEMM: C[M][N] = A[M][256] @ Wt[N][256]^T + bias
// MODE 0: -> Q (prescaled 1/16, rows s>=2048, row-major), K (row-major),
//            Vp (transposed [d][kv], kv bits2<->3 swapped within each 32-block
//            so attn's PV A-fragment is one contiguous 16B read)
// MODE 1: A=attn_out bf16 (M=8192, N=256) -> f32 d_out
// ---------------------------------------------------------------------------
template<int MODE>
__global__ __launch_bounds__(256) void gemm_kernel(
    const bf16* __restrict__ A, const bf16* __restrict__ Wt,
    const float* __restrict__ bias,
    bf16* __restrict__ Qo, bf16* __restrict__ Ko, bf16* __restrict__ Vpo,
    float* __restrict__ Fo)
{
  const int bm = blockIdx.x * 64;
  const int n0 = blockIdx.y * 128;
  const int tid = threadIdx.x;
  const int lane = tid & 63, w = tid >> 6;
  const int l15 = lane & 15, lg = lane >> 4;

  alignas(16) __shared__ bf16 Alds[64 * 32];
  alignas(16) __shared__ bf16 Wlds[128 * 32];

  f32x4 acc[8] = {};

  for (int k0 = 0; k0 < 256; k0 += 32) {
    __syncthreads();
    {
      int c = tid;
      int row = c >> 2, kc = (c & 3) << 3;
      bf16x8 v = *(const bf16x8*)(A + (size_t)(bm + row) * 256 + k0 + kc);
      *(bf16x8*)((char*)Alds + ((c << 4) ^ (((row >> 1) & 3) << 4))) = v;
    }
    #pragma unroll
    for (int it = 0; it < 2; it++) {
      int c = it * 256 + tid;
      int row = c >> 2, kc = (c & 3) << 3;
      bf16x8 v = *(const bf16x8*)(Wt + (size_t)(n0 + row) * 256 + k0 + kc);
      *(bf16x8*)((char*)Wlds + ((c << 4) ^ (((row >> 1) & 3) << 4))) = v;
    }
    __syncthreads();
    const int arow = w * 16 + l15;
    bf16x8 afr = *(const bf16x8*)((char*)Alds +
        (((arow << 6) + (lg << 4)) ^ (((arow >> 1) & 3) << 4)));
    #pragma unroll
    for (int nt = 0; nt < 8; nt++) {
      const int wrow = nt * 16 + l15;
      bf16x8 bfr = *(const bf16x8*)((char*)Wlds +
          (((wrow << 6) + (lg << 4)) ^ (((wrow >> 1) & 3) << 4)));
      acc[nt] = MFMA16(afr, bfr, acc[nt]);
    }
  }

  #pragma unroll
  for (int nt = 0; nt < 8; nt++) {
    const int n = n0 + nt * 16 + l15;
    const float bv = bias[n];
    const int m0 = bm + w * 16 + lg * 4;
    if (MODE == 0) {
      const int b = m0 >> 12;
      const int s = m0 & 4095;
      if (n < 256) {
        if (s >= 2048) {
          #pragma unroll
          for (int r = 0; r < 4; r++)
            Qo[(size_t)((b * 2048 + s - 2048 + r) * 256 + n)] =
                (bf16)((acc[nt][r] + bv) * 0.0625f);
        }
      } else if (n < 512) {
        #pragma unroll
        for (int r = 0; r < 4; r++)
          Ko[(size_t)(((b << 12) + s + r) * 256 + (n - 256))] =
              (bf16)(acc[nt][r] + bv);
      } else {
        // permuted column: within each 32-block swap kv bits 2 and 3
        const int pos = (s & ~31) + 8 * ((s >> 2) & 3) + 4 * ((s >> 4) & 1);
        bf16x4 st = { (bf16)(acc[nt][0] + bv), (bf16)(acc[nt][1] + bv),
                      (bf16)(acc[nt][2] + bv), (bf16)(acc[nt][3] + bv) };
        *(bf16x4*)(Vpo + (size_t)((b << 8) + (n - 512)) * 4096 + pos) = st;
      }
    } else {
      #pragma unroll
      for (int r = 0; r < 4; r++)
        Fo[(size_t)((m0 + r) * 256 + n)] = acc[nt][r] + bv;
    }
  }
}

// ---------------------------------------------------------------------------
// flash attention, KV-split. 4 waves x 16 q rows = 64 q/block. KV tile = 32.
// Swapped QK^T (S^T = mfma(K,Q)) -> softmax + P fully lane-local.
// T14 async staging: issue tile t+1 global loads into regs right after the
// LDS-ready barrier; write them to LDS at the next iteration's barrier.
// Writes per-split partial (O unnormalized, m, l).
// ---------------------------------------------------------------------------
__global__ __launch_bounds__(256, 2) void attn_kernel(
    const bf16* __restrict__ Qg, const bf16* __restrict__ Kg,
    const bf16* __restrict__ Vpg, float* __restrict__ Opart,
    float* __restrict__ ml, int nsplit, int ntiles)
{
  const int G = nsplit * 4;             // groups = (batch, chunk)
  const int id = blockIdx.x;
  const int g = id % G;                 // consecutive ids cycle groups -> XCDs
  const int m = id / G;                 // q-block within batch, 0..31
  const int b = g / nsplit;
  const int c = g % nsplit;

  const int tid = threadIdx.x;
  const int lane = tid & 63, w = tid >> 6;
  const int l15 = lane & 15, lg = lane >> 4;

  alignas(16) __shared__ bf16 Klds[32 * 256];  // [kv][d], swz ^((kv&7)<<4)
  alignas(16) __shared__ bf16 Vlds[256 * 32];  // [d][kv'], 64B rows: no swz

  const int qrow = b * 2048 + m * 64 + w * 16 + l15;   // global q, [0,8192)
  const bf16* qptr = Qg + (size_t)qrow * 256;
  bf16x8 qf[8];
  #pragma unroll
  for (int ks = 0; ks < 8; ks++)
    qf[ks] = *(const bf16x8*)(qptr + ks * 32 + lg * 8);

  const bf16* Kb = Kg + ((size_t)b * 4096) * 256;
  const bf16* Vb = Vpg + ((size_t)b * 256) * 4096;
  const int kv0base = c * (ntiles * 32);

  bf16x8 kreg[4], vreg[4];
  auto issue = [&](int t) {
    const int kv0 = kv0base + t * 32;
    #pragma unroll
    for (int j = 0; j < 4; j++) {
      const int ck = j * 256 + tid;   // K chunk: row=ck>>5, col8=ck&31
      kreg[j] = *(const bf16x8*)(Kb + (size_t)(kv0 + (ck >> 5)) * 256 +
                                 ((ck & 31) << 3));
      const int cv = j * 256 + tid;   // V chunk: d=cv>>2, col8=cv&3
      vreg[j] = *(const bf16x8*)(Vb + (size_t)(cv >> 2) * 4096 + kv0 +
                                 ((cv & 3) << 3));
    }
  };
  issue(0);

  f32x4 o[16] = {};                   // O^T: d = dt*16+lg*4+r, q = l15
  float m_run = -1e30f, l_run = 0.f;

  for (int t = 0; t < ntiles; t++) {
    __syncthreads();                  // LDS free (tile t-1 consumed)
    #pragma unroll
    for (int j = 0; j < 4; j++) {
      const int ck = j * 256 + tid;
      *(bf16x8*)((char*)Klds + ((ck << 4) ^ (((ck >> 5) & 7) << 4))) = kreg[j];
      const int cv = j * 256 + tid;
      *(bf16x8*)((char*)Vlds + (cv << 4)) = vreg[j];
    }
    __syncthreads();                  // LDS tile t ready
    if (t + 1 < ntiles) issue(t + 1); // overlap with compute below

    // S^T[kv][q]: p[tt] holds kv = tt*16 + lg*4 + r, q = l15
    f32x4 p[2] = {};
    #pragma unroll
    for (int ks = 0; ks < 8; ks++) {
      #pragma unroll
      for (int tt = 0; tt < 2; tt++) {
        const int krow = tt * 16 + l15;
        bf16x8 kf = *(const bf16x8*)((char*)Klds +
            (((krow << 9) + (ks << 6) + (lg << 4)) ^ ((krow & 7) << 4)));
        p[tt] = MFMA16(kf, qf[ks], p[tt]);
      }
    }

    float mt = fmaxf(fmaxf(fmaxf(p[0][0], p[0][1]), fmaxf(p[0][2], p[0][3])),
                     fmaxf(fmaxf(p[1][0], p[1][1]), fmaxf(p[1][2], p[1][3])));
    mt = fmaxf(mt, __shfl_xor(mt, 16));
    mt = fmaxf(mt, __shfl_xor(mt, 32));
    if (!__all(mt <= m_run + 8.f)) {  // defer-max: rescale only on real growth
      const float m_new = fmaxf(m_run, mt);
      const float alpha = __expf(m_run - m_new);
      l_run *= alpha;
      #pragma unroll
      for (int i = 0; i < 16; i++) {
        o[i][0] *= alpha; o[i][1] *= alpha; o[i][2] *= alpha; o[i][3] *= alpha;
      }
      m_run = m_new;
    }

    float psum = 0.f;
    bf16x8 pf;                        // slot e <-> kv = 16*(e>>2)+4*lg+(e&3)
    #pragma unroll
    for (int e = 0; e < 8; e++) {
      float ev = __expf(p[e >> 2][e & 3] - m_run);
      psum += ev;
      pf[e] = (bf16)ev;
    }
    psum += __shfl_xor(psum, 16);
    psum += __shfl_xor(psum, 32);
    l_run += psum;

    // O^T += Vp . P  (Vp rows give k-slots matching pf's kappa map)
    #pragma unroll
    for (int dt = 0; dt < 16; dt++) {
      const int drow = dt * 16 + l15;
      bf16x8 af = *(const bf16x8*)((char*)Vlds + (drow << 6) + (lg << 4));
      o[dt] = MFMA16(af, pf, o[dt]);
    }
  }

  float* op = Opart + ((size_t)c * 8192 + qrow) * 256;
  #pragma unroll
  for (int dt = 0; dt < 16; dt++)
    *(f32x4*)(op + dt * 16 + lg * 4) = o[dt];
  if (lg == 0) {
    ml[((size_t)c * 8192 + qrow) * 2] = m_run;
    ml[((size_t)c * 8192 + qrow) * 2 + 1] = l_run;
  }
}

// ---------------------------------------------------------------------------
// combine: AO[q][d] = sum_s exp(m_s - M) O_s[q][d] / sum_s exp(m_s - M) l_s
// ---------------------------------------------------------------------------
__global__ __launch_bounds__(256) void combine_kernel(
    const float* __restrict__ Opart, const float* __restrict__ ml,
    bf16* __restrict__ AO, int nsplit)
{
  const int id = blockIdx.x * 256 + threadIdx.x;   // q*64 + dchunk
  const int q = id >> 6, dc = (id & 63) << 2;
  float M = -1e30f;
  for (int s = 0; s < nsplit; s++)
    M = fmaxf(M, ml[((size_t)s * 8192 + q) * 2]);
  float L = 0.f;
  f32x4 acc = {};
  for (int s = 0; s < nsplit; s++) {
    const float mm = ml[((size_t)s * 8192 + q) * 2];
    const float ll = ml[((size_t)s * 8192 + q) * 2 + 1];
    const float wgt = __expf(mm - M);
    L += ll * wgt;
    f32x4 v = *(const f32x4*)(Opart + ((size_t)s * 8192 + q) * 256 + dc);
    acc[0] += wgt * v[0]; acc[1] += wgt * v[1];
    acc[2] += wgt * v[2]; acc[3] += wgt * v[3];
  }
  const float inv = 1.f / L;
  bf16x4 st = { (bf16)(acc[0] * inv), (bf16)(acc[1] * inv),
                (bf16)(acc[2] * inv), (bf16)(acc[3] * inv) };
  *(bf16x4*)(AO + (size_t)q * 256 + dc) = st;
}

// ---------------------------------------------------------------------------
extern "C" void kernel_launch(void* const* d_in, const int* in_sizes, int n_in,
                              void* d_out, int out_size, void* d_ws, size_t ws_size,
                              hipStream_t stream) {
  const float* x    = (const float*)d_in[0];
  const float* px   = (const float*)d_in[1];
  const float* Wqkv = (const float*)d_in[2];
  const float* bqkv = (const float*)d_in[3];
  const float* Wout = (const float*)d_in[4];
  const float* bout = (const float*)d_in[5];
  float* out = (float*)d_out;

  char* ws = (char*)d_ws;
  bf16* Qbf   = (bf16*)(ws);                          // 4 MB [8192][256] (*1/16)
  bf16* Kbf   = (bf16*)(ws + (4u << 20));             // 8 MB [4][4096][256]
  bf16* Vp    = (bf16*)(ws + (12u << 20));            // 8 MB [4][256][4096] perm
  bf16* Woutt = (bf16*)(ws + (20u << 20));            // 128 KB
  bf16* Wqkvt = (bf16*)(ws + (20u << 20) + (1u << 17)); // 384 KB (dead post-gemm0)
  bf16* Xbf   = (bf16*)(ws + (21u << 20));            // 8 MB (dead post-gemm0)
  float* Opart = (float*)(ws + (21u << 20));          // nsplit*8 MB (overlaps Xbf)
  bf16* AObf  = (bf16*)(ws);                          // reuses Q region post-attn

  // pick KV-split by available workspace
  int nsplit = 1;
  if (ws_size >= (size_t)(21u << 20) + 4u * 8388608u + 262144u) nsplit = 4;
  else if (ws_size >= (size_t)(21u << 20) + 2u * 8388608u + 262144u) nsplit = 2;
  float* ml = (float*)(ws + (21u << 20) + (size_t)nsplit * 8388608u);
  const int ntiles = (4096 / nsplit) / 32;

  prep_kernel<<<dim3(512), dim3(256), 0, stream>>>(x, px, Wqkv, Wout,
                                                   Xbf, Wqkvt, Woutt);
  gemm_kernel<0><<<dim3(256, 6), dim3(256), 0, stream>>>(
      Xbf, Wqkvt, bqkv, Qbf, Kbf, Vp, nullptr);
  attn_kernel<<<dim3(128 * nsplit), dim3(256), 0, stream>>>(
      Qbf, Kbf, Vp, Opart, ml, nsplit, ntiles);
  combine_kernel<<<dim3(2048), dim3(256), 0, stream>>>(Opart, ml, AObf, nsplit);
  gemm_kernel<1><<<dim3(128, 2), dim3(256), 0, stream>>>(
      AObf, Woutt, bout, nullptr, nullptr, nullptr, out);
}

// Round 7
// 96.174 us; speedup vs baseline: 3.6956x; 1.0976x over previous
//
#include <hip/hip_runtime.h>

typedef __bf16 bf16;
typedef __attribute__((ext_vector_type(8))) __bf16 bf16x8;
typedef __attribute__((ext_vector_type(4))) __bf16 bf16x4;
typedef __attribute__((ext_vector_type(4))) float f32x4;
typedef __attribute__((ext_vector_type(16))) float f32x16;
typedef __attribute__((ext_vector_type(4))) unsigned u32x4;

#define MFMA16(a, b, c) __builtin_amdgcn_mfma_f32_16x16x32_bf16(a, b, c, 0, 0, 0)
#define MFMA32(a, b, c) __builtin_amdgcn_mfma_f32_32x32x16_bf16(a, b, c, 0, 0, 0)

__device__ inline void gload_lds16(const void* g, void* l) {
  __builtin_amdgcn_global_load_lds(
      (const __attribute__((address_space(1))) void*)g,
      (__attribute__((address_space(3))) void*)l, 16, 0, 0);
}

__device__ inline unsigned packbf(float a, float b) {
  unsigned short x = __builtin_bit_cast(unsigned short, (bf16)a);
  unsigned short y = __builtin_bit_cast(unsigned short, (bf16)b);
  return (unsigned)x | ((unsigned)y << 16);
}

// ---------------------------------------------------------------------------
// prep: Xbf = bf16(concat(prev_x, x)); Wqkvt[768][256], Woutt[256][256] = W^T
// ---------------------------------------------------------------------------
__global__ __launch_bounds__(256) void prep_kernel(
    const float* __restrict__ x, const float* __restrict__ px,
    const float* __restrict__ Wqkv, const float* __restrict__ Wout,
    bf16* __restrict__ Xbf, bf16* __restrict__ Wqkvt, bf16* __restrict__ Woutt)
{
  int tid = blockIdx.x * 256 + threadIdx.x;
  int nth = gridDim.x * 256;
  for (int i = tid; i < (4 * 4096 * 256) / 4; i += nth) {
    int e = i << 2;
    int b = e >> 20;
    int r = e & 1048575;
    const float* src = (r < 524288) ? (px + (b << 19) + r)
                                    : (x + (b << 19) + (r - 524288));
    float4 f = *(const float4*)src;
    bf16x4 o = { (bf16)f.x, (bf16)f.y, (bf16)f.z, (bf16)f.w };
    *(bf16x4*)(Xbf + e) = o;
  }
  for (int i = tid; i < 768 * 256; i += nth) {
    int n = i >> 8, k = i & 255;
    Wqkvt[i] = (bf16)Wqkv[k * 768 + n];
  }
  for (int i = tid; i < 256 * 256; i += nth) {
    int n = i >> 8, k = i & 255;
    Woutt[i] = (bf16)Wout[k * 256 + n];
  }
}

// ---------------------------------------------------------------------------
// GEMM: C[M][N] = A[M][256] @ Wt[N][256]^T + bias
// MODE 0: writes Q/K/V in MFMA-FRAGMENT order for the 32x32x16 attention:
//   Qp  [qg][ks 16][lane 64][e 8]           (q = qg*32 + (lane&31), prescaled)
//   KVp [b*128+T][ K: ks*512 | V: 8192 + (s*8+dg)*512 ][lane*8 + e]
// MODE 1: A = attn-out bf16 (M=8192) -> f32 d_out
// ---------------------------------------------------------------------------
template<int MODE>
__global__ __launch_bounds__(256) void gemm_kernel(
    const bf16* __restrict__ A, const bf16* __restrict__ Wt,
    const float* __restrict__ bias,
    bf16* __restrict__ Qo, bf16* __restrict__ KVo, float* __restrict__ Fo)
{
  const int bm = blockIdx.x * 64;
  const int n0 = blockIdx.y * 128;
  const int tid = threadIdx.x;
  const int lane = tid & 63, w = tid >> 6;
  const int l15 = lane & 15, lg = lane >> 4;

  alignas(16) __shared__ bf16 Alds[64 * 32];
  alignas(16) __shared__ bf16 Wlds[128 * 32];

  f32x4 acc[8] = {};

  for (int k0 = 0; k0 < 256; k0 += 32) {
    __syncthreads();
    {
      int c = tid;
      int row = c >> 2, kc = (c & 3) << 3;
      bf16x8 v = *(const bf16x8*)(A + (size_t)(bm + row) * 256 + k0 + kc);
      *(bf16x8*)((char*)Alds + ((c << 4) ^ (((row >> 1) & 3) << 4))) = v;
    }
    #pragma unroll
    for (int it = 0; it < 2; it++) {
      int c = it * 256 + tid;
      int row = c >> 2, kc = (c & 3) << 3;
      bf16x8 v = *(const bf16x8*)(Wt + (size_t)(n0 + row) * 256 + k0 + kc);
      *(bf16x8*)((char*)Wlds + ((c << 4) ^ (((row >> 1) & 3) << 4))) = v;
    }
    __syncthreads();
    const int arow = w * 16 + l15;
    bf16x8 afr = *(const bf16x8*)((char*)Alds +
        (((arow << 6) + (lg << 4)) ^ (((arow >> 1) & 3) << 4)));
    #pragma unroll
    for (int nt = 0; nt < 8; nt++) {
      const int wrow = nt * 16 + l15;
      bf16x8 bfr = *(const bf16x8*)((char*)Wlds +
          (((wrow << 6) + (lg << 4)) ^ (((wrow >> 1) & 3) << 4)));
      acc[nt] = MFMA16(afr, bfr, acc[nt]);
    }
  }

  #pragma unroll
  for (int nt = 0; nt < 8; nt++) {
    const int n = n0 + nt * 16 + l15;
    const float bv = bias[n];
    const int m0 = bm + w * 16 + lg * 4;
    if (MODE == 0) {
      const int bq = m0 >> 12;
      const int s = m0 & 4095;
      if (n < 256) {
        if (s >= 2048) {
          const int ks = n >> 4, h2 = (n >> 3) & 1, e = n & 7;
          #pragma unroll
          for (int r = 0; r < 4; r++) {
            const int qrow = bq * 2048 + (s - 2048) + r;
            Qo[(size_t)(qrow >> 5) * 8192 + ks * 512 +
               ((qrow & 31) + 32 * h2) * 8 + e] =
                (bf16)((acc[nt][r] + bv) * 0.0625f);
          }
        }
      } else if (n < 512) {
        const int d = n - 256;
        const int ks = d >> 4, h2 = (d >> 3) & 1, e = d & 7;
        const size_t tb = (size_t)(bq * 128 + (s >> 5)) * 16384;
        #pragma unroll
        for (int r = 0; r < 4; r++)
          KVo[tb + ks * 512 + (((s & 31) + r) + 32 * h2) * 8 + e] =
              (bf16)(acc[nt][r] + bv);
      } else {
        const int d = n - 512;
        const int kv32 = s & 31;
        const int sidx = kv32 >> 4, h2 = (kv32 >> 3) & 1, e0 = kv32 & 7;
        bf16x4 st = { (bf16)(acc[nt][0] + bv), (bf16)(acc[nt][1] + bv),
                      (bf16)(acc[nt][2] + bv), (bf16)(acc[nt][3] + bv) };
        *(bf16x4*)(KVo + (size_t)(bq * 128 + (s >> 5)) * 16384 + 8192 +
                   (sidx * 8 + (d >> 5)) * 512 + ((d & 31) + 32 * h2) * 8 + e0) = st;
      }
    } else {
      #pragma unroll
      for (int r = 0; r < 4; r++)
        Fo[(size_t)((m0 + r) * 256 + n)] = acc[nt][r] + bv;
    }
  }
}

// ---------------------------------------------------------------------------
// flash attention: 32x32x16 MFMA, q=32/wave, 4 waves = 128 q/block.
// KV-split 8 -> 512 blocks. Fragment-ordered global K/V -> linear
// global_load_lds staging (dbuf), conflict-free lane-linear ds_read_b128.
// Swapped QK^T (S^T = mfma(K,Q)); P B-frags via pack + shfl_xor(32) exchange
// (replaces permlane32_swap whose operand semantics mis-paired half the kv).
// ---------------------------------------------------------------------------
__global__ __launch_bounds__(256, 2) void attn_kernel(
    const bf16* __restrict__ Qp, const bf16* __restrict__ KVp,
    bf16* __restrict__ Opart, float* __restrict__ ml)
{
  const int id = blockIdx.x;
  const int c = id & 7;            // kv chunk -> XCD affinity (id%8)
  const int b = (id >> 3) & 3;     // batch
  const int qb = id >> 5;          // q block 0..15
  const int tid = threadIdx.x;
  const int lane = tid & 63, w = tid >> 6;
  const int l31 = lane & 31, hi = lane >> 5;

  __shared__ bf16 lds[2][16384];   // [buf][ K frags 0..8191 | V frags 8192.. ]

  // Q fragments (fragment-ordered global, lane-contiguous 1KB loads)
  const int qg = b * 64 + qb * 4 + w;
  const bf16* qbase = Qp + (size_t)qg * 8192 + lane * 8;
  bf16x8 qf[16];
  #pragma unroll
  for (int ks = 0; ks < 16; ks++)
    qf[ks] = *(const bf16x8*)(qbase + ks * 512);

  const bf16* kvtile0 = KVp + (size_t)(b * 128 + c * 16) * 16384;

  auto stage = [&](int t) {
    const char* g = (const char*)(kvtile0 + (size_t)t * 16384) + w * 8192 + lane * 16;
    char* l = (char*)&lds[t & 1][0] + w * 8192;
    #pragma unroll
    for (int j = 0; j < 8; j++)
      gload_lds16(g + j * 1024, l + j * 1024);
  };
  stage(0);

  f32x16 o[8] = {};                // O^T[d][q]: q = l31, d = dg*32+8*(r>>2)+4*hi+(r&3)
  float m_run = -1e30f, l_run = 0.f;

  for (int t = 0; t < 16; t++) {
    __syncthreads();               // tile t landed; buf^1 free
    if (t + 1 < 16) stage(t + 1);
    const bf16* kbuf = &lds[t & 1][0];
    const bf16* vbuf = kbuf + 8192;

    // S^T[kv][q]: lane holds 16 kv values for q = l31 (kv=(r&3)+8*(r>>2)+4*hi)
    f32x16 p = {};
    __builtin_amdgcn_s_setprio(1);
    #pragma unroll
    for (int ks = 0; ks < 16; ks++) {
      bf16x8 kf = *(const bf16x8*)(kbuf + ks * 512 + lane * 8);
      p = MFMA32(kf, qf[ks], p);
    }
    __builtin_amdgcn_s_setprio(0);

    float mt = fmaxf(p[0], p[1]);
    #pragma unroll
    for (int i = 2; i < 16; i++) mt = fmaxf(mt, p[i]);
    mt = fmaxf(mt, __shfl_xor(mt, 32));
    if (!__all(mt <= m_run + 8.f)) {   // defer-max (T13)
      const float m_new = fmaxf(m_run, mt);
      const float alpha = __expf(m_run - m_new);
      l_run *= alpha;
      #pragma unroll
      for (int i = 0; i < 8; i++)
        #pragma unroll
        for (int j = 0; j < 16; j++) o[i][j] *= alpha;
      m_run = m_new;
    }
    float ps = 0.f;
    #pragma unroll
    for (int i = 0; i < 16; i++) { p[i] = __expf(p[i] - m_run); ps += p[i]; }
    ps += __shfl_xor(ps, 32);
    l_run += ps;

    // P -> B-frags. Lane (q,hi) holds kv j at word u[i]:
    //   hi=0: u0..u7 = kv(0,1)(2,3)(8,9)(10,11)(16,17)(18,19)(24,25)(26,27)
    //   hi=1: u0..u7 = kv(4,5)(6,7)(12,13)(14,15)(20,21)(22,23)(28,29)(30,31)
    // B-frag word j of pf0 needs kv(8*hi+2j, 8*hi+2j+1); pf1: +16.
    // Exchange via shfl_xor(32): unambiguous cross-half swap.
    unsigned u[8], xp[8];
    #pragma unroll
    for (int i = 0; i < 8; i++) u[i] = packbf(p[2 * i], p[2 * i + 1]);
    #pragma unroll
    for (int i = 0; i < 8; i++)
      xp[i] = (unsigned)__shfl_xor((int)u[i], 32);
    const u32x4 w0 = hi ? (u32x4){xp[2], xp[3], u[2], u[3]}
                        : (u32x4){u[0], u[1], xp[0], xp[1]};
    const u32x4 w1 = hi ? (u32x4){xp[6], xp[7], u[6], u[7]}
                        : (u32x4){u[4], u[5], xp[4], xp[5]};
    const bf16x8 pf0 = __builtin_bit_cast(bf16x8, w0);
    const bf16x8 pf1 = __builtin_bit_cast(bf16x8, w1);

    // O^T += V^T . P
    __builtin_amdgcn_s_setprio(1);
    #pragma unroll
    for (int dg = 0; dg < 8; dg++) {
      bf16x8 v0 = *(const bf16x8*)(vbuf + dg * 512 + lane * 8);
      o[dg] = MFMA32(v0, pf0, o[dg]);
      bf16x8 v1 = *(const bf16x8*)(vbuf + (8 + dg) * 512 + lane * 8);
      o[dg] = MFMA32(v1, pf1, o[dg]);
    }
    __builtin_amdgcn_s_setprio(0);
  }

  const int q = b * 2048 + qb * 128 + w * 32 + l31;
  bf16* ob = Opart + ((size_t)c * 8192 + q) * 256;
  #pragma unroll
  for (int dg = 0; dg < 8; dg++) {
    #pragma unroll
    for (int r4 = 0; r4 < 4; r4++) {
      const int d = dg * 32 + r4 * 8 + hi * 4;
      bf16x4 st = { (bf16)o[dg][r4 * 4 + 0], (bf16)o[dg][r4 * 4 + 1],
                    (bf16)o[dg][r4 * 4 + 2], (bf16)o[dg][r4 * 4 + 3] };
      *(bf16x4*)(ob + d) = st;
    }
  }
  if (hi == 0) {
    float2 v = { m_run, l_run };
    *(float2*)(ml + ((size_t)c * 8192 + q) * 2) = v;
  }
}

// ---------------------------------------------------------------------------
// combine the 8 KV-split partials
// ---------------------------------------------------------------------------
__global__ __launch_bounds__(256) void combine_kernel(
    const bf16* __restrict__ Opart, const float* __restrict__ ml,
    bf16* __restrict__ AO)
{
  const int id = blockIdx.x * 256 + threadIdx.x;   // q*32 + dchunk
  const int q = id >> 5, dc = (id & 31) << 3;
  float ms[8], ls[8], M = -1e30f;
  #pragma unroll
  for (int s = 0; s < 8; s++) {
    float2 v = *(const float2*)(ml + ((size_t)s * 8192 + q) * 2);
    ms[s] = v.x; ls[s] = v.y;
    M = fmaxf(M, v.x);
  }
  float L = 0.f;
  float acc[8] = {};
  #pragma unroll
  for (int s = 0; s < 8; s++) {
    const float wgt = __expf(ms[s] - M);
    L += ls[s] * wgt;
    bf16x8 v = *(const bf16x8*)(Opart + ((size_t)s * 8192 + q) * 256 + dc);
    #pragma unroll
    for (int j = 0; j < 8; j++) acc[j] += wgt * (float)v[j];
  }
  const float inv = 1.f / L;
  bf16x8 st;
  #pragma unroll
  for (int j = 0; j < 8; j++) st[j] = (bf16)(acc[j] * inv);
  *(bf16x8*)(AO + (size_t)q * 256 + dc) = st;
}

// ---------------------------------------------------------------------------
extern "C" void kernel_launch(void* const* d_in, const int* in_sizes, int n_in,
                              void* d_out, int out_size, void* d_ws, size_t ws_size,
                              hipStream_t stream) {
  const float* x    = (const float*)d_in[0];
  const float* px   = (const float*)d_in[1];
  const float* Wqkv = (const float*)d_in[2];
  const float* bqkv = (const float*)d_in[3];
  const float* Wout = (const float*)d_in[4];
  const float* bout = (const float*)d_in[5];
  float* out = (float*)d_out;

  char* ws = (char*)d_ws;
  bf16* Qp    = (bf16*)(ws);                    //  4 MB frag-ordered Q (*1/16)
  bf16* KVp   = (bf16*)(ws + 4194304);          // 16 MB frag-ordered K|V tiles
  bf16* Woutt = (bf16*)(ws + 20971520);         // 128 KB
  bf16* Wqkvt = (bf16*)(ws + 21102592);         // 384 KB
  float* ml   = (float*)(ws + 21495808);        // 512 KB [8][8192][2]
  bf16* Xbf   = (bf16*)(ws + 22020096);         //  8 MB (dead after gemm0)
  bf16* Opart = (bf16*)(ws + 22020096);         // 32 MB [8][8192][256] (reuses Xbf)
  bf16* AObf  = (bf16*)(ws);                    //  4 MB (reuses Qp after attn)

  prep_kernel<<<dim3(512), dim3(256), 0, stream>>>(x, px, Wqkv, Wout,
                                                   Xbf, Wqkvt, Woutt);
  gemm_kernel<0><<<dim3(256, 6), dim3(256), 0, stream>>>(
      Xbf, Wqkvt, bqkv, Qp, KVp, nullptr);
  attn_kernel<<<dim3(512), dim3(256), 0, stream>>>(Qp, KVp, Opart, ml);
  combine_kernel<<<dim3(1024), dim3(256), 0, stream>>>(Opart, ml, AObf);
  gemm_kernel<1><<<dim3(128, 2), dim3(256), 0, stream>>>(
      AObf, Woutt, bout, nullptr, nullptr, out);
}